// Round 6
// baseline (242.670 us; speedup 1.0000x reference)
//
#include <hip/hip_runtime.h>

typedef int i32x4 __attribute__((ext_vector_type(4)));

#define AS1 __attribute__((address_space(1)))
#define AS3 __attribute__((address_space(3)))

#define M_DIM 8192
#define N_DIM 8192
#define K_DIM 2048
#define NT 32   // K-tiles of 64 bytes

// ---------------- quantize x: per-tensor scale, 16 elems/thread ----------------
__global__ __launch_bounds__(256) void quant_x_kernel(
    const float* __restrict__ x, const float* __restrict__ in_scale,
    i32x4* __restrict__ qx, int n16)
{
    int idx = blockIdx.x * 256 + threadIdx.x;
    if (idx >= n16) return;
    float s = in_scale[0];
    const float4* xp = reinterpret_cast<const float4*>(x) + (size_t)idx * 4;
    union { char c[16]; i32x4 v; } u;
#pragma unroll
    for (int v4 = 0; v4 < 4; ++v4) {
        float4 f = xp[v4];
        u.c[v4*4+0] = (char)(int)fminf(fmaxf(rintf(f.x / s), -128.f), 127.f);
        u.c[v4*4+1] = (char)(int)fminf(fmaxf(rintf(f.y / s), -128.f), 127.f);
        u.c[v4*4+2] = (char)(int)fminf(fmaxf(rintf(f.z / s), -128.f), 127.f);
        u.c[v4*4+3] = (char)(int)fminf(fmaxf(rintf(f.w / s), -128.f), 127.f);
    }
    qx[idx] = u.v;
}

// ---------------- quantize w: per-row (out-channel) scale ----------------
__global__ __launch_bounds__(256) void quant_w_kernel(
    const float* __restrict__ w, const float* __restrict__ w_scale,
    i32x4* __restrict__ qw, int n16)
{
    int idx = blockIdx.x * 256 + threadIdx.x;
    if (idx >= n16) return;
    float s = w_scale[idx >> 7];   // K=2048 -> 128 threads (of 16 elems) per row
    const float4* wp = reinterpret_cast<const float4*>(w) + (size_t)idx * 4;
    union { char c[16]; i32x4 v; } u;
#pragma unroll
    for (int v4 = 0; v4 < 4; ++v4) {
        float4 f = wp[v4];
        u.c[v4*4+0] = (char)(int)fminf(fmaxf(rintf(f.x / s), -128.f), 127.f);
        u.c[v4*4+1] = (char)(int)fminf(fmaxf(rintf(f.y / s), -128.f), 127.f);
        u.c[v4*4+2] = (char)(int)fminf(fmaxf(rintf(f.z / s), -128.f), 127.f);
        u.c[v4*4+3] = (char)(int)fminf(fmaxf(rintf(f.w / s), -128.f), 127.f);
    }
    qw[idx] = u.v;
}

// ---------------- per-out-channel combined scale + dequantized bias ----------------
__global__ __launch_bounds__(256) void prep_kernel(
    const float* __restrict__ bias, const float* __restrict__ in_scale,
    const float* __restrict__ w_scale, const float* __restrict__ b_scale,
    float* __restrict__ oscale, float* __restrict__ obias, int n)
{
    int i = blockIdx.x * 256 + threadIdx.x;
    if (i >= n) return;
    oscale[i] = in_scale[0] * w_scale[i] * 0.5f;   // W_ALPHA
    float bs = b_scale[i];
    float q = fminf(fmaxf(rintf(bias[i] / bs), -128.f), 127.f);
    obias[i] = q * bs * 0.75f;                      // B_BETA
}

// ---------------- int8 GEMM: 256x256 tile, 2-deep ring, 2 blocks/CU ----------------
// 8 waves (2M x 4N), per-wave 128x64 output = 8x4 frags of mfma_i32_16x16x64_i8.
// 2 phases/K-tile, 16 MFMA per phase. LDS: 2 bufs x (A 16KB + B 16KB) = 64 KiB
// -> 2 blocks/CU co-resident (the m114 TLP mechanism: block B's MFMAs cover
// block A's barrier/LDS/vmcnt stalls). VGPR must stay <=128 for 4 waves/SIMD.
// Swizzle slot' = kg ^ ((row>>1)&3), inverse-swizzled global src -> 0 conflicts (R2).
// Ring safety: STAGE(tt+1) in phase a overwrites buffer holding tile tt-1, whose
// reads all completed before tt's opening barrier. Gate vmcnt(0) at end of
// phase b (~1400 cy after issue), before the closing barrier / tt+1's reads.
// NOTE: min-waves-per-EU MUST be 2 — acc=128 regs; bound of 4 spills (R3: 6x regress).
__global__ __launch_bounds__(512, 2) void gemm_i8_kernel(
    const char* __restrict__ qx,   // [M][K] int8
    const char* __restrict__ qw,   // [N][K] int8
    const float* __restrict__ oscale,
    const float* __restrict__ obias,
    float* __restrict__ out)       // [M][N] fp32
{
    __shared__ __align__(16) char ldsA[2 * 16384];
    __shared__ __align__(16) char ldsB[2 * 16384];

    const int t    = threadIdx.x;          // 0..511
    const int lane = t & 63;
    const int wid  = t >> 6;               // 0..7
    const int wm   = wid >> 2;             // 0..1
    const int wn   = wid & 3;              // 0..3

    // XCD-aware swizzle: 1024 blocks, 1024 % 8 == 0 -> bijective
    int bid = blockIdx.x;
    int sid = (bid & 7) * 128 + (bid >> 3);
    const size_t brow = (size_t)(sid >> 5) * 256;
    const size_t bcol = (size_t)(sid & 31) * 256;

    // staging: thread t covers LDS row t/4 (+128 on _HI), 16B slot t&3 (linear dest).
    // Global source pre-swizzled: logical slot = (t&3) ^ ((row>>1)&3) = (t&3) ^ ((t>>3)&3).
    const int srow  = t >> 2;
    const int lslot = (t & 3) ^ ((t >> 3) & 3);
    const char* gA = qx + (brow + srow) * K_DIM + lslot * 16;
    const char* gB = qw + (bcol + srow) * K_DIM + lslot * 16;
    char* dstA = ldsA + t * 16;
    char* dstB = ldsB + t * 16;

#define SA_LO(tt_) __builtin_amdgcn_global_load_lds((const AS1 unsigned int*)(gA + (tt_) * 64), \
        (AS3 unsigned int*)(dstA + ((tt_) & 1) * 16384), 16, 0, 0)
#define SA_HI(tt_) __builtin_amdgcn_global_load_lds((const AS1 unsigned int*)(gA + (tt_) * 64 + 128 * K_DIM), \
        (AS3 unsigned int*)(dstA + ((tt_) & 1) * 16384 + 8192), 16, 0, 0)
#define SB_LO(tt_) __builtin_amdgcn_global_load_lds((const AS1 unsigned int*)(gB + (tt_) * 64), \
        (AS3 unsigned int*)(dstB + ((tt_) & 1) * 16384), 16, 0, 0)
#define SB_HI(tt_) __builtin_amdgcn_global_load_lds((const AS1 unsigned int*)(gB + (tt_) * 64 + 128 * K_DIM), \
        (AS3 unsigned int*)(dstB + ((tt_) & 1) * 16384 + 8192), 16, 0, 0)

    // per-lane fragment read offsets (swizzled), constant across tiles
    const int lrow = lane & 15;
    const int kg   = lane >> 4;            // 16B k-group 0..3
    int offA[8], offB[4];
#pragma unroll
    for (int m = 0; m < 8; ++m) {
        int r = wm * 128 + m * 16 + lrow;
        offA[m] = r * 64 + ((kg ^ ((r >> 1) & 3)) * 16);
    }
#pragma unroll
    for (int n = 0; n < 4; ++n) {
        int r = wn * 64 + n * 16 + lrow;
        offB[n] = r * 64 + ((kg ^ ((r >> 1) & 3)) * 16);
    }

    i32x4 acc[8][4];
#pragma unroll
    for (int m = 0; m < 8; ++m)
#pragma unroll
        for (int n = 0; n < 4; ++n)
            acc[m][n] = (i32x4){0, 0, 0, 0};

#define MM(m_, n_, a_, b_) acc[m_][n_] = __builtin_amdgcn_mfma_i32_16x16x64_i8((a_), (b_), acc[m_][n_], 0, 0, 0)
#define BAR() do { __builtin_amdgcn_s_barrier(); asm volatile("" ::: "memory"); } while (0)
#define LGKM0() do { asm volatile("s_waitcnt lgkmcnt(0)" ::: "memory"); __builtin_amdgcn_sched_barrier(0); } while (0)
#define VMCNT0() asm volatile("s_waitcnt vmcnt(0)" ::: "memory")

    // prologue: tile 0 staged and drained
    SA_LO(0); SA_HI(0); SB_LO(0); SB_HI(0);
    VMCNT0();
    BAR();

    for (int tt = 0; tt < NT; ++tt) {
        const char* bA = ldsA + (tt & 1) * 16384;
        const char* bB = ldsB + (tt & 1) * 16384;
        const bool pf = (tt + 1) < NT;

        // ---- phase a: 8 ds_read + full stage of tile tt+1; MFMA m0-3 x n0-3
        i32x4 a0 = *(const i32x4*)(bA + offA[0]);
        i32x4 a1 = *(const i32x4*)(bA + offA[1]);
        i32x4 a2 = *(const i32x4*)(bA + offA[2]);
        i32x4 a3 = *(const i32x4*)(bA + offA[3]);
        i32x4 b0 = *(const i32x4*)(bB + offB[0]);
        i32x4 b1 = *(const i32x4*)(bB + offB[1]);
        i32x4 b2 = *(const i32x4*)(bB + offB[2]);
        i32x4 b3 = *(const i32x4*)(bB + offB[3]);
        if (pf) { SA_LO(tt + 1); SA_HI(tt + 1); SB_LO(tt + 1); SB_HI(tt + 1); }
        BAR();
        LGKM0();
        __builtin_amdgcn_s_setprio(1);
        MM(0,0,a0,b0); MM(0,1,a0,b1); MM(0,2,a0,b2); MM(0,3,a0,b3);
        MM(1,0,a1,b0); MM(1,1,a1,b1); MM(1,2,a1,b2); MM(1,3,a1,b3);
        MM(2,0,a2,b0); MM(2,1,a2,b1); MM(2,2,a2,b2); MM(2,3,a2,b3);
        MM(3,0,a3,b0); MM(3,1,a3,b1); MM(3,2,a3,b2); MM(3,3,a3,b3);
        __builtin_amdgcn_s_setprio(0);
        BAR();

        // ---- phase b: 4 ds_read; MFMA m4-7 x n0-3; vmcnt(0) gate; closing barrier
        a0 = *(const i32x4*)(bA + offA[4]);
        a1 = *(const i32x4*)(bA + offA[5]);
        a2 = *(const i32x4*)(bA + offA[6]);
        a3 = *(const i32x4*)(bA + offA[7]);
        BAR();
        LGKM0();
        __builtin_amdgcn_s_setprio(1);
        MM(4,0,a0,b0); MM(4,1,a0,b1); MM(4,2,a0,b2); MM(4,3,a0,b3);
        MM(5,0,a1,b0); MM(5,1,a1,b1); MM(5,2,a1,b2); MM(5,3,a1,b3);
        MM(6,0,a2,b0); MM(6,1,a2,b1); MM(6,2,a2,b2); MM(6,3,a2,b3);
        MM(7,0,a3,b0); MM(7,1,a3,b1); MM(7,2,a3,b2); MM(7,3,a3,b3);
        __builtin_amdgcn_s_setprio(0);
        if (pf) VMCNT0();   // tile tt+1's 4 loads landed; ~1400cy of cover since issue
        BAR();              // closing barrier doubles as tt+1's data-visibility gate
    }
#undef SA_LO
#undef SA_HI
#undef SB_LO
#undef SB_HI
#undef MM
#undef BAR
#undef LGKM0
#undef VMCNT0

    // epilogue: C/D layout col = lane&15, row = (lane>>4)*4 + j
    const int colq = lane & 15;
    const int rowq = lane >> 4;
#pragma unroll
    for (int n = 0; n < 4; ++n) {
        size_t col = bcol + wn * 64 + n * 16 + colq;
        float sc = oscale[col];
        float bi = obias[col];
#pragma unroll
        for (int m = 0; m < 8; ++m) {
            size_t rbase = brow + wm * 128 + m * 16 + (size_t)rowq * 4;
#pragma unroll
            for (int j = 0; j < 4; ++j)
                out[(rbase + j) * N_DIM + col] = (float)acc[m][n][j] * sc + bi;
        }
    }
}

extern "C" void kernel_launch(void* const* d_in, const int* in_sizes, int n_in,
                              void* d_out, int out_size, void* d_ws, size_t ws_size,
                              hipStream_t stream) {
    const float* x        = (const float*)d_in[0];
    const float* weight   = (const float*)d_in[1];
    const float* bias     = (const float*)d_in[2];
    const float* in_scale = (const float*)d_in[3];
    const float* w_scale  = (const float*)d_in[4];
    const float* b_scale  = (const float*)d_in[5];
    float* out = (float*)d_out;

    char* ws = (char*)d_ws;
    const size_t xk = (size_t)M_DIM * K_DIM;
    const size_t wk = (size_t)N_DIM * K_DIM;
    char*  qx     = ws;
    char*  qw     = ws + xk;
    float* oscale = (float*)(ws + xk + wk);
    float* obias  = oscale + N_DIM;

    const int n16 = (int)(xk / 16);   // 1,048,576 = 4096 * 256
    quant_x_kernel<<<4096, 256, 0, stream>>>(x, in_scale, (i32x4*)qx, n16);
    quant_w_kernel<<<4096, 256, 0, stream>>>(weight, w_scale, (i32x4*)qw, n16);
    prep_kernel<<<32, 256, 0, stream>>>(bias, in_scale, w_scale, b_scale, oscale, obias, N_DIM);

    gemm_i8_kernel<<<1024, 512, 0, stream>>>(qx, qw, oscale, obias, out);
}

// Round 7
// 238.201 us; speedup vs baseline: 1.0188x; 1.0188x over previous
//
#include <hip/hip_runtime.h>

typedef int i32x4 __attribute__((ext_vector_type(4)));

#define AS1 __attribute__((address_space(1)))
#define AS3 __attribute__((address_space(3)))

#define M_DIM 8192
#define N_DIM 8192
#define K_DIM 2048
#define NT 32   // K-tiles of 64 bytes

// ---------------- quantize x: per-tensor scale, 16 elems/thread ----------------
__global__ __launch_bounds__(256) void quant_x_kernel(
    const float* __restrict__ x, const float* __restrict__ in_scale,
    i32x4* __restrict__ qx, int n16)
{
    int idx = blockIdx.x * 256 + threadIdx.x;
    if (idx >= n16) return;
    float s = in_scale[0];
    const float4* xp = reinterpret_cast<const float4*>(x) + (size_t)idx * 4;
    union { char c[16]; i32x4 v; } u;
#pragma unroll
    for (int v4 = 0; v4 < 4; ++v4) {
        float4 f = xp[v4];
        u.c[v4*4+0] = (char)(int)fminf(fmaxf(rintf(f.x / s), -128.f), 127.f);
        u.c[v4*4+1] = (char)(int)fminf(fmaxf(rintf(f.y / s), -128.f), 127.f);
        u.c[v4*4+2] = (char)(int)fminf(fmaxf(rintf(f.z / s), -128.f), 127.f);
        u.c[v4*4+3] = (char)(int)fminf(fmaxf(rintf(f.w / s), -128.f), 127.f);
    }
    qx[idx] = u.v;
}

// ---------------- quantize w: per-row (out-channel) scale ----------------
__global__ __launch_bounds__(256) void quant_w_kernel(
    const float* __restrict__ w, const float* __restrict__ w_scale,
    i32x4* __restrict__ qw, int n16)
{
    int idx = blockIdx.x * 256 + threadIdx.x;
    if (idx >= n16) return;
    float s = w_scale[idx >> 7];   // K=2048 -> 128 threads (of 16 elems) per row
    const float4* wp = reinterpret_cast<const float4*>(w) + (size_t)idx * 4;
    union { char c[16]; i32x4 v; } u;
#pragma unroll
    for (int v4 = 0; v4 < 4; ++v4) {
        float4 f = wp[v4];
        u.c[v4*4+0] = (char)(int)fminf(fmaxf(rintf(f.x / s), -128.f), 127.f);
        u.c[v4*4+1] = (char)(int)fminf(fmaxf(rintf(f.y / s), -128.f), 127.f);
        u.c[v4*4+2] = (char)(int)fminf(fmaxf(rintf(f.z / s), -128.f), 127.f);
        u.c[v4*4+3] = (char)(int)fminf(fmaxf(rintf(f.w / s), -128.f), 127.f);
    }
    qw[idx] = u.v;
}

// ---------------- per-out-channel combined scale + dequantized bias ----------------
__global__ __launch_bounds__(256) void prep_kernel(
    const float* __restrict__ bias, const float* __restrict__ in_scale,
    const float* __restrict__ w_scale, const float* __restrict__ b_scale,
    float* __restrict__ oscale, float* __restrict__ obias, int n)
{
    int i = blockIdx.x * 256 + threadIdx.x;
    if (i >= n) return;
    oscale[i] = in_scale[0] * w_scale[i] * 0.5f;   // W_ALPHA
    float bs = b_scale[i];
    float q = fminf(fmaxf(rintf(bias[i] / bs), -128.f), 127.f);
    obias[i] = q * bs * 0.75f;                      // B_BETA
}

// ---------------- int8 GEMM: 256x256, 4-deep ring, reg-pipelined (ds_read under MFMA) ----
// 8 waves (2M x 4N), per-wave 128x64 output = 8x4 frags of mfma_i32_16x16x64_i8.
// Per K-tile: issue A-high reads -> 16 MFMA (A-low x B, reads in flight) ->
// issue NEXT tile's A-low+B reads -> 16 MFMA (A-high x B, reads in flight) ->
// stage(t+3) -> vmcnt(4) -> ONE barrier. Compiler emits the counted lgkmcnt(4/8)
// waits from dependency tracking; sched_barrier(0) pins cluster order.
// Ring/slot ledger: gate at end of tile T retires stage(T+2) (vmcnt(4) with
// {T+2,T+3} outstanding); barrier then certifies slot (T+2)&3 -> reads of tile
// T+1's frags during tile T are certified by the gate at end of T-1. Stage at
// tile T writes slot (T+3)&3, disjoint from slots T&3, (T+1)&3 being read.
// NOTE: min-waves-per-EU MUST stay 2 — acc=128 AGPR; bound of 4 spills (R3: 6x).
__global__ __launch_bounds__(512, 2) void gemm_i8_kernel(
    const char* __restrict__ qx,   // [M][K] int8
    const char* __restrict__ qw,   // [N][K] int8
    const float* __restrict__ oscale,
    const float* __restrict__ obias,
    float* __restrict__ out)       // [M][N] fp32
{
    __shared__ __align__(16) char ldsA[4 * 16384];
    __shared__ __align__(16) char ldsB[4 * 16384];

    const int t    = threadIdx.x;          // 0..511
    const int lane = t & 63;
    const int wid  = t >> 6;               // 0..7
    const int wm   = wid >> 2;             // 0..1
    const int wn   = wid & 3;              // 0..3

    // XCD-aware swizzle: 1024 blocks, 1024 % 8 == 0 -> bijective
    int bid = blockIdx.x;
    int sid = (bid & 7) * 128 + (bid >> 3);
    const size_t brow = (size_t)(sid >> 5) * 256;
    const size_t bcol = (size_t)(sid & 31) * 256;

    // staging: thread t covers LDS row t/4 (+128 on _HI), 16B slot t&3 (linear dest).
    // Global source pre-swizzled: logical slot = (t&3) ^ ((t>>3)&3)  (rule 21).
    const int srow  = t >> 2;
    const int lslot = (t & 3) ^ ((t >> 3) & 3);
    const char* gA = qx + (brow + srow) * K_DIM + lslot * 16;
    const char* gB = qw + (bcol + srow) * K_DIM + lslot * 16;
    char* dstA = ldsA + t * 16;
    char* dstB = ldsB + t * 16;

#define STAGE4(tt_) do {                                                                  \
    __builtin_amdgcn_global_load_lds((const AS1 unsigned int*)(gA + (tt_) * 64),          \
        (AS3 unsigned int*)(dstA + ((tt_) & 3) * 16384), 16, 0, 0);                       \
    __builtin_amdgcn_global_load_lds((const AS1 unsigned int*)(gA + (tt_) * 64 + 128 * K_DIM), \
        (AS3 unsigned int*)(dstA + ((tt_) & 3) * 16384 + 8192), 16, 0, 0);                \
    __builtin_amdgcn_global_load_lds((const AS1 unsigned int*)(gB + (tt_) * 64),          \
        (AS3 unsigned int*)(dstB + ((tt_) & 3) * 16384), 16, 0, 0);                       \
    __builtin_amdgcn_global_load_lds((const AS1 unsigned int*)(gB + (tt_) * 64 + 128 * K_DIM), \
        (AS3 unsigned int*)(dstB + ((tt_) & 3) * 16384 + 8192), 16, 0, 0);                \
  } while (0)

    // Swizzled base offsets. The swizzle term (kg ^ ((r>>1)&3)) is invariant
    // under r += 16*m (16 rows = +8 in r>>1, = 0 mod 4), so frag m/n is just
    // base + m*1024 (folds into the ds_read offset: immediate). 2 VGPRs total.
    const int lrow = lane & 15;
    const int kg   = lane >> 4;            // 16B k-group 0..3
    const int rA   = wm * 128 + lrow;
    const int rB   = wn * 64 + lrow;
    const int offA0 = rA * 64 + ((kg ^ ((rA >> 1) & 3)) * 16);
    const int offB0 = rB * 64 + ((kg ^ ((rB >> 1) & 3)) * 16);

    i32x4 acc[8][4];
#pragma unroll
    for (int m = 0; m < 8; ++m)
#pragma unroll
        for (int n = 0; n < 4; ++n)
            acc[m][n] = (i32x4){0, 0, 0, 0};

#define MM(m_, n_, a_, b_) acc[m_][n_] = __builtin_amdgcn_mfma_i32_16x16x64_i8((a_), (b_), acc[m_][n_], 0, 0, 0)
#define BAR() do { __builtin_amdgcn_s_barrier(); asm volatile("" ::: "memory"); } while (0)
#define SBAR() __builtin_amdgcn_sched_barrier(0)

    // K-tile body. BC*: current B frags; BN*: next-tile B frags (written if READS_).
    // GATE_: 0 = vmcnt(4)+BAR (steady), 1 = vmcnt(0)+BAR (t=29), 2 = none (t>=30).
#define KBODY(tt_, BC0,BC1,BC2,BC3, BN0,BN1,BN2,BN3, READS_, STAGE_, GATE_) do {          \
    const char* bAp = ldsA + ((tt_) & 3) * 16384;                                         \
    i32x4 hA0 = *(const i32x4*)(bAp + offA0 + 4096);                                      \
    i32x4 hA1 = *(const i32x4*)(bAp + offA0 + 5120);                                      \
    i32x4 hA2 = *(const i32x4*)(bAp + offA0 + 6144);                                      \
    i32x4 hA3 = *(const i32x4*)(bAp + offA0 + 7168);                                      \
    SBAR();                                                                               \
    __builtin_amdgcn_s_setprio(1);                                                        \
    MM(0,0,cA0,BC0); MM(0,1,cA0,BC1); MM(0,2,cA0,BC2); MM(0,3,cA0,BC3);                   \
    MM(1,0,cA1,BC0); MM(1,1,cA1,BC1); MM(1,2,cA1,BC2); MM(1,3,cA1,BC3);                   \
    MM(2,0,cA2,BC0); MM(2,1,cA2,BC1); MM(2,2,cA2,BC2); MM(2,3,cA2,BC3);                   \
    MM(3,0,cA3,BC0); MM(3,1,cA3,BC1); MM(3,2,cA3,BC2); MM(3,3,cA3,BC3);                   \
    __builtin_amdgcn_s_setprio(0);                                                        \
    SBAR();                                                                               \
    if (READS_) {                                                                         \
        const char* nAp = ldsA + (((tt_) + 1) & 3) * 16384;                               \
        const char* nBp = ldsB + (((tt_) + 1) & 3) * 16384;                               \
        cA0 = *(const i32x4*)(nAp + offA0);                                               \
        cA1 = *(const i32x4*)(nAp + offA0 + 1024);                                        \
        cA2 = *(const i32x4*)(nAp + offA0 + 2048);                                        \
        cA3 = *(const i32x4*)(nAp + offA0 + 3072);                                        \
        BN0 = *(const i32x4*)(nBp + offB0);                                               \
        BN1 = *(const i32x4*)(nBp + offB0 + 1024);                                        \
        BN2 = *(const i32x4*)(nBp + offB0 + 2048);                                        \
        BN3 = *(const i32x4*)(nBp + offB0 + 3072);                                        \
    }                                                                                     \
    SBAR();                                                                               \
    __builtin_amdgcn_s_setprio(1);                                                        \
    MM(4,0,hA0,BC0); MM(4,1,hA0,BC1); MM(4,2,hA0,BC2); MM(4,3,hA0,BC3);                   \
    MM(5,0,hA1,BC0); MM(5,1,hA1,BC1); MM(5,2,hA1,BC2); MM(5,3,hA1,BC3);                   \
    MM(6,0,hA2,BC0); MM(6,1,hA2,BC1); MM(6,2,hA2,BC2); MM(6,3,hA2,BC3);                   \
    MM(7,0,hA3,BC0); MM(7,1,hA3,BC1); MM(7,2,hA3,BC2); MM(7,3,hA3,BC3);                   \
    __builtin_amdgcn_s_setprio(0);                                                        \
    SBAR();                                                                               \
    if (STAGE_) STAGE4((tt_) + 3);                                                        \
    if ((GATE_) == 0) { asm volatile("s_waitcnt vmcnt(4)" ::: "memory"); BAR(); SBAR(); } \
    else if ((GATE_) == 1) { asm volatile("s_waitcnt vmcnt(0)" ::: "memory"); BAR(); SBAR(); } \
  } while (0)

    // prologue: stage tiles 0,1,2; retire 0,1 (keep 2 in flight); load tile-0 frags
    STAGE4(0); STAGE4(1); STAGE4(2);
    asm volatile("s_waitcnt vmcnt(4)" ::: "memory");
    BAR();
    SBAR();
    i32x4 cA0 = *(const i32x4*)(ldsA + offA0);
    i32x4 cA1 = *(const i32x4*)(ldsA + offA0 + 1024);
    i32x4 cA2 = *(const i32x4*)(ldsA + offA0 + 2048);
    i32x4 cA3 = *(const i32x4*)(ldsA + offA0 + 3072);
    i32x4 Bx0 = *(const i32x4*)(ldsB + offB0);
    i32x4 Bx1 = *(const i32x4*)(ldsB + offB0 + 1024);
    i32x4 Bx2 = *(const i32x4*)(ldsB + offB0 + 2048);
    i32x4 Bx3 = *(const i32x4*)(ldsB + offB0 + 3072);
    i32x4 By0, By1, By2, By3;

    for (int it = 0; it < 14; ++it) {     // tiles 0..27
        const int t0 = 2 * it;
        KBODY(t0,     Bx0,Bx1,Bx2,Bx3, By0,By1,By2,By3, 1, 1, 0);
        KBODY(t0 + 1, By0,By1,By2,By3, Bx0,Bx1,Bx2,Bx3, 1, 1, 0);
    }
    // tail: tiles 28..31 (stage 31 at t=28; drain at t=29; no gates after)
    KBODY(28, Bx0,Bx1,Bx2,Bx3, By0,By1,By2,By3, 1, 1, 0);
    KBODY(29, By0,By1,By2,By3, Bx0,Bx1,Bx2,Bx3, 1, 0, 1);
    KBODY(30, Bx0,Bx1,Bx2,Bx3, By0,By1,By2,By3, 1, 0, 2);
    KBODY(31, By0,By1,By2,By3, Bx0,Bx1,Bx2,Bx3, 0, 0, 2);

#undef KBODY
#undef STAGE4
#undef MM
#undef BAR
#undef SBAR

    // epilogue: C/D layout col = lane&15, row = (lane>>4)*4 + j
    const int colq = lane & 15;
    const int rowq = lane >> 4;
#pragma unroll
    for (int n = 0; n < 4; ++n) {
        size_t col = bcol + wn * 64 + n * 16 + colq;
        float sc = oscale[col];
        float bi = obias[col];
#pragma unroll
        for (int m = 0; m < 8; ++m) {
            size_t rbase = brow + wm * 128 + m * 16 + (size_t)rowq * 4;
#pragma unroll
            for (int j = 0; j < 4; ++j)
                out[(rbase + j) * N_DIM + col] = (float)acc[m][n][j] * sc + bi;
        }
    }
}

extern "C" void kernel_launch(void* const* d_in, const int* in_sizes, int n_in,
                              void* d_out, int out_size, void* d_ws, size_t ws_size,
                              hipStream_t stream) {
    const float* x        = (const float*)d_in[0];
    const float* weight   = (const float*)d_in[1];
    const float* bias     = (const float*)d_in[2];
    const float* in_scale = (const float*)d_in[3];
    const float* w_scale  = (const float*)d_in[4];
    const float* b_scale  = (const float*)d_in[5];
    float* out = (float*)d_out;

    char* ws = (char*)d_ws;
    const size_t xk = (size_t)M_DIM * K_DIM;
    const size_t wk = (size_t)N_DIM * K_DIM;
    char*  qx     = ws;
    char*  qw     = ws + xk;
    float* oscale = (float*)(ws + xk + wk);
    float* obias  = oscale + N_DIM;

    const int n16 = (int)(xk / 16);   // 1,048,576 = 4096 * 256
    quant_x_kernel<<<4096, 256, 0, stream>>>(x, in_scale, (i32x4*)qx, n16);
    quant_w_kernel<<<4096, 256, 0, stream>>>(weight, w_scale, (i32x4*)qw, n16);
    prep_kernel<<<32, 256, 0, stream>>>(bias, in_scale, w_scale, b_scale, oscale, obias, N_DIM);

    gemm_i8_kernel<<<1024, 512, 0, stream>>>(qx, qw, oscale, obias, out);
}